// Round 2
// baseline (185.766 us; speedup 1.0000x reference)
//
#include <hip/hip_runtime.h>
#include <hip/hip_bf16.h>
#include <stdint.h>

// Problem constants (from reference setup_inputs)
#define BATCH 8
#define TC 2048   // M
#define TQ 1024   // K
#define DD 1024   // N

typedef __attribute__((ext_vector_type(8))) __bf16 bf16x8;
typedef __attribute__((ext_vector_type(4))) float f32x4;

__device__ __forceinline__ ushort f2bf(float f) {
    uint32_t u = __float_as_uint(f);
    uint32_t r = (u + 0x7fffu + ((u >> 16) & 1u)) >> 16;  // RNE
    return (ushort)r;
}

// ---------------------------------------------------------------------------
// Kernel 1 (fused prep): blocks [0,4096) do wave-per-row softmax -> bf16 attn;
// blocks [4096,6144) do 64x64 transpose+cast of qencode -> qt.   (UNCHANGED)
// ---------------------------------------------------------------------------
__global__ __launch_bounds__(256) void prep(const float* __restrict__ sim,
                                            const float* __restrict__ qen,
                                            ushort* __restrict__ attn,
                                            ushort* __restrict__ qt) {
    __shared__ float tile[64][65];
    const int t = threadIdx.x;
    if (blockIdx.x < 4096) {
        // ---- softmax: one wave per row of 1024 ----
        const int wid = t >> 6;
        const int lane = t & 63;
        const int row = blockIdx.x * 4 + wid;
        const float4* src = (const float4*)(sim + (size_t)row * TQ);

        float4 x[4];
        #pragma unroll
        for (int j = 0; j < 4; j++) x[j] = src[lane + 64 * j];

        float m = -INFINITY;
        #pragma unroll
        for (int j = 0; j < 4; j++)
            m = fmaxf(m, fmaxf(fmaxf(x[j].x, x[j].y), fmaxf(x[j].z, x[j].w)));
        #pragma unroll
        for (int o = 32; o >= 1; o >>= 1) m = fmaxf(m, __shfl_xor(m, o));

        const float L2E = 1.4426950408889634f;
        float e[4][4];
        float s = 0.f;
        #pragma unroll
        for (int j = 0; j < 4; j++) {
            e[j][0] = exp2f((x[j].x - m) * L2E);
            e[j][1] = exp2f((x[j].y - m) * L2E);
            e[j][2] = exp2f((x[j].z - m) * L2E);
            e[j][3] = exp2f((x[j].w - m) * L2E);
            s += (e[j][0] + e[j][1]) + (e[j][2] + e[j][3]);
        }
        #pragma unroll
        for (int o = 32; o >= 1; o >>= 1) s += __shfl_xor(s, o);
        const float inv = 1.0f / s;

        ushort4* dst = (ushort4*)(attn + (size_t)row * TQ);
        #pragma unroll
        for (int j = 0; j < 4; j++) {
            ushort4 o4;
            o4.x = f2bf(e[j][0] * inv);
            o4.y = f2bf(e[j][1] * inv);
            o4.z = f2bf(e[j][2] * inv);
            o4.w = f2bf(e[j][3] * inv);
            dst[lane + 64 * j] = o4;
        }
    } else {
        // ---- transpose+cast: qencode [b][q][d] fp32 -> qt [b][d][q] bf16 ----
        const int bid = blockIdx.x - 4096;
        const int b = bid >> 8;             // 256 tiles per batch (16x16)
        const int rem = bid & 255;
        const int q0 = (rem >> 4) * 64;
        const int d0 = (rem & 15) * 64;
        const int r = t >> 4;               // 0..15
        const int c = (t & 15) * 4;         // 0..60

        #pragma unroll
        for (int it = 0; it < 4; it++) {
            float4 v = *(const float4*)(qen + ((size_t)b * TQ + q0 + r + it * 16) * DD + d0 + c);
            tile[r + it * 16][c + 0] = v.x;
            tile[r + it * 16][c + 1] = v.y;
            tile[r + it * 16][c + 2] = v.z;
            tile[r + it * 16][c + 3] = v.w;
        }
        __syncthreads();

        #pragma unroll
        for (int it = 0; it < 4; it++) {
            const int d = (t >> 4) + it * 16;
            const int qq = (t & 15) * 4;
            ushort4 o4;
            o4.x = f2bf(tile[qq + 0][d]);
            o4.y = f2bf(tile[qq + 1][d]);
            o4.z = f2bf(tile[qq + 2][d]);
            o4.w = f2bf(tile[qq + 3][d]);
            *(ushort4*)(qt + ((size_t)b * DD + d0 + d) * TQ + q0 + qq) = o4;
        }
    }
}

// ---------------------------------------------------------------------------
// Kernel 2: batched GEMM  C[b] = A[b] (MxK bf16) x Bt[b]^T (NxK bf16)
// 256x256 tile, BK=64, 8 waves (2m x 4n), grid 256 (1 block/CU, batch/XCD).
//
// R2 change: single-barrier counted-lgkmcnt pipeline.  Per K-tile, 8
// sub-phases of 8 MFMA; each sub-phase ISSUES the next sub-phase's ds_reads,
// then waits lgkmcnt(N)=just-issued (never a drain), then MFMAs -> LDS port
// drains under the MFMA pipe.  Staging for tile X+1 targets buf^1 while all
// tile-X reads target buf, so the only cross-wave joint is ONE barrier per
// K-tile (16 total), preceded by per-wave vmcnt(0) with ~8 sub-phases of
// latency cover.  asm waitcnts are scheduling pins; hipcc still inserts its
// own dependency waits, so correctness does not rest on the counts.
//
// LDS swizzle (carried, verified conflict-free): slot (row r, 16B-chunk s)
// holds global chunk s ^ (r&7); staged with linear global_load_lds dest +
// pre-swizzled global source; fragment read chunk = (ss*4+quad) ^ (l16&7).
//
// Quadrant x k-substep order LL0,LL1,LH0,LH1,HH0,HH1,HL0,HL1 with a Blo
// re-read at HL (28 reads/tile, +4 over minimal) caps fragment liveness at
// ~96 VGPR so acc(128)+frags fits the 256-VGPR / 2-waves-per-SIMD budget.
// ---------------------------------------------------------------------------
#define BAR()    __builtin_amdgcn_s_barrier()
#define LGKM(n)  asm volatile("s_waitcnt lgkmcnt(" #n ")" ::: "memory")
#define VMCNT0() asm volatile("s_waitcnt vmcnt(0)" ::: "memory")
#define PRIO(x)  __builtin_amdgcn_s_setprio(x)

__global__ __launch_bounds__(512, 2) void gemm_bf16(const ushort* __restrict__ A,
                                                    const ushort* __restrict__ Bt,
                                                    float* __restrict__ C) {
    __shared__ __align__(16) ushort As[2][2][128][64];   // 64 KiB
    __shared__ __align__(16) ushort Bs[2][2][128][64];   // 64 KiB

    // bijective XCD swizzle: 256 blocks, XCD x gets batch x (32 contiguous tiles)
    const int bid = blockIdx.x;
    const int swz = ((bid & 7) << 5) | (bid >> 3);
    const int b   = swz >> 5;
    const int tm0 = ((swz >> 2) & 7) * 256;
    const int tn0 = (swz & 3) * 256;

    const ushort* Ab = A + (size_t)b * TC * TQ;
    const ushort* Bb = Bt + (size_t)b * DD * TQ;
    float* Cb = C + (size_t)b * TC * DD;

    const int t = threadIdx.x;
    const int wid = t >> 6, lane = t & 63;
    const int quad = lane >> 4, l16 = lane & 15;
    const int wm = wid >> 2;          // 0..1  (m half)
    const int wn = wid & 3;           // 0..3  (n quarter)
    const int wbh = wn >> 1;          // B half this wave reads
    const int wrow = (wn & 1) << 6;   // row offset within B half
    const int rkey = l16 & 7;

    // staging: per thread, per half-tile: 2 x 16B loads (wave-uniform LDS base,
    // lane x 16B appended by HW).  Global source chunk pre-swizzled.
    const int srow = t >> 3;                         // 0..63
    const int gko  = (((t & 7) ^ (srow & 7)) << 3);  // ushort offset in k

    auto stageA = [&](int buf, int h, int kk) {
        const ushort* g0 = Ab + (size_t)(tm0 + h * 128 + srow) * TQ + kk + gko;
        char* l0 = (char*)(&As[buf][h][0][0]) + wid * 1024;
        __builtin_amdgcn_global_load_lds(
            (const __attribute__((address_space(1))) void*)g0,
            (__attribute__((address_space(3))) void*)l0, 16, 0, 0);
        __builtin_amdgcn_global_load_lds(
            (const __attribute__((address_space(1))) void*)(g0 + (size_t)64 * TQ),
            (__attribute__((address_space(3))) void*)(l0 + 8192), 16, 0, 0);
    };
    auto stageB = [&](int buf, int h, int kk) {
        const ushort* g0 = Bb + (size_t)(tn0 + h * 128 + srow) * TQ + kk + gko;
        char* l0 = (char*)(&Bs[buf][h][0][0]) + wid * 1024;
        __builtin_amdgcn_global_load_lds(
            (const __attribute__((address_space(1))) void*)g0,
            (__attribute__((address_space(3))) void*)l0, 16, 0, 0);
        __builtin_amdgcn_global_load_lds(
            (const __attribute__((address_space(1))) void*)(g0 + (size_t)64 * TQ),
            (__attribute__((address_space(3))) void*)(l0 + 8192), 16, 0, 0);
    };

    // fragment reads: rb = 16-row block (0..7) within wave's A half; nb = 16-row
    // block (0..3) within wave's 64 B rows; ss = k substep (0..1).
    auto rdA = [&](int buf, int rb, int ss) -> bf16x8 {
        return *(const bf16x8*)&As[buf][wm][rb * 16 + l16][((ss * 4 + quad) ^ rkey) * 8];
    };
    auto rdB = [&](int buf, int nb, int ss) -> bf16x8 {
        return *(const bf16x8*)&Bs[buf][wbh][wrow + nb * 16 + l16][((ss * 4 + quad) ^ rkey) * 8];
    };

    f32x4 acc[8][4];
    #pragma unroll
    for (int i = 0; i < 8; i++)
        #pragma unroll
        for (int j = 0; j < 4; j++) acc[i][j] = (f32x4){0.f, 0.f, 0.f, 0.f};

    // ---- prologue: stage tile 0 -> buf0; retire (loop-top barrier joins) ----
    stageA(0, 0, 0); stageA(0, 1, 0); stageB(0, 0, 0); stageB(0, 1, 0);
    VMCNT0();

    #pragma unroll 1
    for (int x = 0; x < 16; ++x) {
        const int bs = x & 1;
        // Joint point: all waves' vmcnt(0) (stage of tile x retired) and all
        // lgkmcnt(0) (every buf^1 read of tile x-1 serviced) happened BEFORE
        // this barrier -> safe to read buf and to overwrite buf^1.
        BAR();

        bf16x8 aS0[4], aS1[4], bS0[2], bS1[2], c0[2], c1[2], d0[4], d1[4], e0[2], e1[2];

        // pre: issue F(LL,0) reads [6]
        #pragma unroll
        for (int i = 0; i < 4; i++) aS0[i] = rdA(bs, i, 0);
        #pragma unroll
        for (int i = 0; i < 2; i++) bS0[i] = rdB(bs, i, 0);

        // stage tile x+1 -> buf^1 (8 vm insts; retired by vmcnt(0) at P8)
        if (x < 15) {
            const int kk = (x + 1) * 64;
            stageA(bs ^ 1, 0, kk); stageA(bs ^ 1, 1, kk);
            stageB(bs ^ 1, 0, kk); stageB(bs ^ 1, 1, kk);
        }

        // P1: LL ss0   (issue LL ss1 [6])
        #pragma unroll
        for (int i = 0; i < 4; i++) aS1[i] = rdA(bs, i, 1);
        #pragma unroll
        for (int i = 0; i < 2; i++) bS1[i] = rdB(bs, i, 1);
        LGKM(6); PRIO(1);
        #pragma unroll
        for (int mi = 0; mi < 4; mi++)
            #pragma unroll
            for (int ni = 0; ni < 2; ni++)
                acc[mi][ni] = __builtin_amdgcn_mfma_f32_16x16x32_bf16(
                    aS0[mi], bS0[ni], acc[mi][ni], 0, 0, 0);
        PRIO(0);

        // P2: LL ss1   (issue Bhi ss0 [2])
        #pragma unroll
        for (int i = 0; i < 2; i++) c0[i] = rdB(bs, 2 + i, 0);
        LGKM(2); PRIO(1);
        #pragma unroll
        for (int mi = 0; mi < 4; mi++)
            #pragma unroll
            for (int ni = 0; ni < 2; ni++)
                acc[mi][ni] = __builtin_amdgcn_mfma_f32_16x16x32_bf16(
                    aS1[mi], bS1[ni], acc[mi][ni], 0, 0, 0);
        PRIO(0);

        // P3: LH ss0   (issue Bhi ss1 [2])
        #pragma unroll
        for (int i = 0; i < 2; i++) c1[i] = rdB(bs, 2 + i, 1);
        LGKM(2); PRIO(1);
        #pragma unroll
        for (int mi = 0; mi < 4; mi++)
            #pragma unroll
            for (int ni = 0; ni < 2; ni++)
                acc[mi][2 + ni] = __builtin_amdgcn_mfma_f32_16x16x32_bf16(
                    aS0[mi], c0[ni], acc[mi][2 + ni], 0, 0, 0);
        PRIO(0);

        // P4: LH ss1   (issue Ahi ss0 [4])
        #pragma unroll
        for (int i = 0; i < 4; i++) d0[i] = rdA(bs, 4 + i, 0);
        LGKM(4); PRIO(1);
        #pragma unroll
        for (int mi = 0; mi < 4; mi++)
            #pragma unroll
            for (int ni = 0; ni < 2; ni++)
                acc[mi][2 + ni] = __builtin_amdgcn_mfma_f32_16x16x32_bf16(
                    aS1[mi], c1[ni], acc[mi][2 + ni], 0, 0, 0);
        PRIO(0);

        // P5: HH ss0   (issue Ahi ss1 [4])
        #pragma unroll
        for (int i = 0; i < 4; i++) d1[i] = rdA(bs, 4 + i, 1);
        LGKM(4); PRIO(1);
        #pragma unroll
        for (int mi = 0; mi < 4; mi++)
            #pragma unroll
            for (int ni = 0; ni < 2; ni++)
                acc[4 + mi][2 + ni] = __builtin_amdgcn_mfma_f32_16x16x32_bf16(
                    d0[mi], c0[ni], acc[4 + mi][2 + ni], 0, 0, 0);
        PRIO(0);

        // P6: HH ss1   (issue Blo ss0 re-read [2])
        #pragma unroll
        for (int i = 0; i < 2; i++) e0[i] = rdB(bs, i, 0);
        LGKM(2); PRIO(1);
        #pragma unroll
        for (int mi = 0; mi < 4; mi++)
            #pragma unroll
            for (int ni = 0; ni < 2; ni++)
                acc[4 + mi][2 + ni] = __builtin_amdgcn_mfma_f32_16x16x32_bf16(
                    d1[mi], c1[ni], acc[4 + mi][2 + ni], 0, 0, 0);
        PRIO(0);

        // P7: HL ss0   (issue Blo ss1 re-read [2])
        #pragma unroll
        for (int i = 0; i < 2; i++) e1[i] = rdB(bs, i, 1);
        LGKM(2); PRIO(1);
        #pragma unroll
        for (int mi = 0; mi < 4; mi++)
            #pragma unroll
            for (int ni = 0; ni < 2; ni++)
                acc[4 + mi][ni] = __builtin_amdgcn_mfma_f32_16x16x32_bf16(
                    d0[mi], e0[ni], acc[4 + mi][ni], 0, 0, 0);
        PRIO(0);

        // P8: HL ss1   (no new reads)
        LGKM(0); PRIO(1);
        #pragma unroll
        for (int mi = 0; mi < 4; mi++)
            #pragma unroll
            for (int ni = 0; ni < 2; ni++)
                acc[4 + mi][ni] = __builtin_amdgcn_mfma_f32_16x16x32_bf16(
                    d1[mi], e1[ni], acc[4 + mi][ni], 0, 0, 0);
        PRIO(0);
        if (x < 15) VMCNT0();   // stage(x+1) retired; ~8 sub-phases of cover
    }

    // ---- C write: C/D layout col=l16, row=quad*4+reg ----
    #pragma unroll
    for (int mi = 0; mi < 8; ++mi) {
        const int r0 = tm0 + wm * 128 + mi * 16 + quad * 4;
        #pragma unroll
        for (int ni = 0; ni < 4; ++ni) {
            const int c = tn0 + wn * 64 + ni * 16 + l16;
            f32x4 v = acc[mi][ni];
            #pragma unroll
            for (int r = 0; r < 4; ++r) Cb[(size_t)(r0 + r) * DD + c] = v[r];
        }
    }
}

// ---------------------------------------------------------------------------
extern "C" void kernel_launch(void* const* d_in, const int* in_sizes, int n_in,
                              void* d_out, int out_size, void* d_ws, size_t ws_size,
                              hipStream_t stream) {
    const float* sim = (const float*)d_in[0];   // [8, 2048, 1024]
    const float* qen = (const float*)d_in[1];   // [8, 1024, 1024]
    float* out = (float*)d_out;                 // [8, 2048, 1024]

    ushort* attn = (ushort*)d_ws;                                  // 32 MiB bf16
    ushort* qt = (ushort*)d_ws + (size_t)BATCH * TC * TQ;          // 16 MiB bf16

    prep<<<4096 + 2048, 256, 0, stream>>>(sim, qen, attn, qt);
    gemm_bf16<<<BATCH * (TC / 256) * (DD / 256), 512, 0, stream>>>(attn, qt, out);
}